// Round 1
// baseline (318.206 us; speedup 1.0000x reference)
//
#include <hip/hip_runtime.h>
#include <hip/hip_bf16.h>

#define N_NODES 100000
#define N_EDGES 1600000
#define IN_CH 50
#define NPB 256                                   // nodes per bucket (dst >> 8)
#define NB ((N_NODES + NPB - 1) / NPB)            // 391 buckets
#define CAPLOG 13                                 // 8192 slots/bucket (max ~4.4K used)
#define EPB 4096
#define NBLK_A ((N_EDGES + EPB - 1) / EPB)        // 391 bin blocks
#define PAD_BLOCKS ((N_NODES * 64) / 1024)        // 6250 pad blocks (1024 thr)

// ---- 1. bin edges into fixed-capacity buckets (+ extra blocks: pad x->xb bf16) ----
// cursor_rel[b] is RELATIVE (starts 0 via memset); slot = (b<<CAPLOG) + rel.
__global__ __launch_bounds__(1024) void bin_pad_kernel(
    const int* __restrict__ src, const int* __restrict__ dst,
    int* __restrict__ cursor_rel, unsigned* __restrict__ binned,
    const float* __restrict__ x, unsigned short* __restrict__ xb) {
    if (blockIdx.x >= NBLK_A) {                    // pad lane
        int t = (blockIdx.x - NBLK_A) * 1024 + threadIdx.x;  // < N_NODES*64
        int n = t >> 6, c = t & 63;
        float v = (c < IN_CH) ? x[n * IN_CH + c] : 0.0f;
        __hip_bfloat16 hb = __float2bfloat16(v);
        xb[t] = *(unsigned short*)&hb;
        return;
    }
    __shared__ int bc[NB];
    __shared__ int boff[NB];
    int t = threadIdx.x;
    if (t < NB) bc[t] = 0;
    __syncthreads();
    int e0 = blockIdx.x * EPB;
    int e1 = min(e0 + EPB, N_EDGES);
    for (int i = e0 + t; i < e1; i += 1024)
        atomicAdd(&bc[dst[i] >> 8], 1);
    __syncthreads();
    if (t < NB) {
        int v = bc[t];
        int rel = v ? atomicAdd(&cursor_rel[t], v) : 0;
        boff[t] = (t << CAPLOG) + rel;
        bc[t] = 0;                                 // reuse as local cursor
    }
    __syncthreads();
    for (int i = e0 + t; i < e1; i += 1024) {
        int d = dst[i];
        int b = d >> 8;
        int k = atomicAdd(&bc[b], 1);
        binned[boff[b] + k] = ((unsigned)(d & 255) << 17) | (unsigned)src[i];
    }
}

// ---- 2. per-bucket fine sort (u32 payload) -> cnt, row_start, csr_src ----
// 391 blocks x 1024 threads: ~1.5 blocks/CU.
__global__ __launch_bounds__(1024) void bucket_fine(
    const unsigned* __restrict__ binned, const int* __restrict__ cursor_rel,
    int* __restrict__ cnt, int* __restrict__ row_start, int* __restrict__ csr_src) {
    __shared__ int lcnt[NPB];
    __shared__ int lofs[NPB];
    __shared__ int sc[NPB];
    int t = threadIdx.x;
    int b = blockIdx.x;
    int nbase = b * NPB;
    int bbase = b << CAPLOG;
    int ecnt  = cursor_rel[b];
    if (t < NPB) lcnt[t] = 0;
    __syncthreads();
    for (int i = t; i < ecnt; i += 1024)
        atomicAdd(&lcnt[(binned[bbase + i] >> 17) & 255], 1);
    __syncthreads();
    int v = (t < NPB) ? lcnt[t] : 0;
    if (t < NPB) sc[t] = v;
    __syncthreads();
    for (int off = 1; off < NPB; off <<= 1) {      // Hillis-Steele over 256
        int tmp = (t < NPB && t >= off) ? sc[t - off] : 0;
        __syncthreads();
        if (t < NPB) sc[t] += tmp;
        __syncthreads();
    }
    if (t < NPB) {
        int excl = sc[t] - v;
        lofs[t] = excl;
        int n = nbase + t;
        if (n < N_NODES) { cnt[n] = v; row_start[n] = bbase + excl; }
    }
    __syncthreads();
    for (int i = t; i < ecnt; i += 1024) {
        unsigned p = binned[bbase + i];
        int d = (int)((p >> 17) & 255);
        int k = atomicAdd(&lofs[d], 1);
        csr_src[bbase + k] = (int)(p & 0x1FFFFu);
    }
}

// unpack 8 bf16 from uint4, predicated fma into acc[0..8)
__device__ __forceinline__ void upadd8(float* a, uint4 v, float p) {
    a[0] = fmaf(p, __uint_as_float(v.x << 16), a[0]);
    a[1] = fmaf(p, __uint_as_float(v.x & 0xffff0000u), a[1]);
    a[2] = fmaf(p, __uint_as_float(v.y << 16), a[2]);
    a[3] = fmaf(p, __uint_as_float(v.y & 0xffff0000u), a[3]);
    a[4] = fmaf(p, __uint_as_float(v.z << 16), a[4]);
    a[5] = fmaf(p, __uint_as_float(v.z & 0xffff0000u), a[5]);
    a[6] = fmaf(p, __uint_as_float(v.w << 16), a[6]);
    a[7] = fmaf(p, __uint_as_float(v.w & 0xffff0000u), a[7]);
}

// wave-local LDS fence: LDS ops of one wave complete in order; no block barrier.
#define WAVE_LDS_FENCE() __asm__ volatile("s_waitcnt lgkmcnt(0)" ::: "memory")

// Gather-mean of 4 nodes per wave, software-pipelined (R16): chunk k+1's 8 loads
// are issued BEFORE chunk k's FMA block, so the FMA waitcnt keeps 8 loads in
// flight. All loads are unconditional-safe (sv defaults to 0 -> featb row 0,
// predicated off by p0/p1); FMA-only work stays under uniform guards.
__device__ __forceinline__ void gather4(
    const unsigned short* __restrict__ featb, const int* __restrict__ csr_src,
    const int* __restrict__ row_start, const int* __restrict__ cnt,
    int nb, int lane, float acc[4][8]) {
    int g  = lane >> 3;
    int cw = (lane & 7) * 8;
    int start[4], deg[4], sv[4];
    int dmax = 0;
    #pragma unroll
    for (int i = 0; i < 4; ++i) {
        start[i] = row_start[nb + i];
        deg[i]   = cnt[nb + i];
        dmax = max(dmax, deg[i]);
        #pragma unroll
        for (int c = 0; c < 8; ++c) acc[i][c] = 0.f;
    }
    #pragma unroll
    for (int i = 0; i < 4; ++i)
        sv[i] = (lane < deg[i]) ? csr_src[start[i] + lane] : 0;

    // prologue: issue chunk-0 loads for all 4 nodes
    uint4 a0[4], a1[4];
    #pragma unroll
    for (int i = 0; i < 4; ++i) {
        int s0 = __shfl(sv[i], g);
        int s1 = __shfl(sv[i], 8 + g);
        a0[i] = *(const uint4*)(featb + s0 * 64 + cw);
        a1[i] = *(const uint4*)(featb + s1 * 64 + cw);
    }

    #pragma unroll
    for (int cb = 0; cb < 64; cb += 16) {
        if (cb >= dmax) break;                 // wave-uniform
        bool more = (cb + 16) < dmax;          // wave-uniform
        uint4 b0[4], b1[4];
        if (more) {                            // prefetch next chunk: loads only
            #pragma unroll
            for (int i = 0; i < 4; ++i) {
                int s0 = __shfl(sv[i], cb + 16 + g);
                int s1 = __shfl(sv[i], cb + 24 + g);
                b0[i] = *(const uint4*)(featb + s0 * 64 + cw);
                b1[i] = *(const uint4*)(featb + s1 * 64 + cw);
            }
        }
        #pragma unroll
        for (int i = 0; i < 4; ++i) {
            int rem = deg[i] - cb;
            if (rem > 0) {                     // wave-uniform, pure VALU inside
                float p0 = (g < rem) ? 1.f : 0.f;
                float p1 = (g + 8 < rem) ? 1.f : 0.f;
                upadd8(acc[i], a0[i], p0);
                upadd8(acc[i], a1[i], p1);
            }
        }
        if (more) {
            #pragma unroll
            for (int i = 0; i < 4; ++i) { a0[i] = b0[i]; a1[i] = b1[i]; }
        }
    }
    if (dmax > 64) {                           // rare tail (Poisson(16): ~never)
        for (int i = 0; i < 4; ++i) {
            for (int c0 = 64; c0 < deg[i]; c0 += 64) {
                int rem = deg[i] - c0; if (rem > 64) rem = 64;
                int sx = (lane < rem) ? csr_src[start[i] + c0 + lane] : 0;
                for (int cb = 0; cb < rem; cb += 16) {
                    int s0 = __shfl(sx, cb + g);
                    int s1 = __shfl(sx, cb + 8 + g);
                    float p0 = (cb + g < rem) ? 1.f : 0.f;
                    float p1 = (cb + 8 + g < rem) ? 1.f : 0.f;
                    uint4 v0 = *(const uint4*)(featb + s0 * 64 + cw);
                    uint4 v1 = *(const uint4*)(featb + s1 * 64 + cw);
                    upadd8(acc[i], v0, p0);
                    upadd8(acc[i], v1, p1);
                }
            }
        }
    }
    #pragma unroll
    for (int i = 0; i < 4; ++i) {
        float inv = 1.0f / fmaxf((float)deg[i], 1.0f);
        #pragma unroll
        for (int c = 0; c < 8; ++c) {
            float t = acc[i][c];
            t += __shfl_xor(t, 8);
            t += __shfl_xor(t, 16);
            t += __shfl_xor(t, 32);
            acc[i][c] = t * inv;
        }
    }
}

__device__ __forceinline__ float bf16u(unsigned short u) {
    return __uint_as_float(((unsigned)u) << 16);
}

// ---- 3. layer 1 (R13/R15-proven): 4 nodes/wave; gather(xb) + scalar-broadcast GEMM ----
__global__ __launch_bounds__(256) void layer1_fused(
    const unsigned short* __restrict__ xb,
    const int* __restrict__ csr_src, const int* __restrict__ row_start,
    const int* __restrict__ cnt, const float* __restrict__ W1,
    const float* __restrict__ b1, unsigned short* __restrict__ h1b) {
    int wv   = threadIdx.x >> 6;
    int lane = threadIdx.x & 63;
    int nb   = (blockIdx.x * 4 + wv) * 4;      // N_NODES % 16 == 0

    float acc[4][8];
    gather4(xb, csr_src, row_start, cnt, nb, lane, acc);

    __shared__ __align__(16) float selfF[4][4][64];
    __shared__ __align__(16) float meanF[4][4][64];
    #pragma unroll
    for (int i = 0; i < 4; ++i) {
        selfF[wv][i][lane] = bf16u(xb[((nb + i) << 6) + lane]);
        if (lane < 8) {
            *(float4*)&meanF[wv][i][lane * 8] =
                make_float4(acc[i][0], acc[i][1], acc[i][2], acc[i][3]);
            *(float4*)&meanF[wv][i][lane * 8 + 4] =
                make_float4(acc[i][4], acc[i][5], acc[i][6], acc[i][7]);
        }
    }
    WAVE_LDS_FENCE();

    float ao[4];
    float bb = b1[lane];
    #pragma unroll
    for (int i = 0; i < 4; ++i) ao[i] = bb;
    #pragma unroll
    for (int k = 0; k < IN_CH; ++k) {
        float w = W1[k * 64 + lane];           // lanes coalesced, reused x4
        #pragma unroll
        for (int i = 0; i < 4; ++i) ao[i] = fmaf(selfF[wv][i][k], w, ao[i]);
    }
    #pragma unroll
    for (int k = 0; k < IN_CH; ++k) {
        float w = W1[(IN_CH + k) * 64 + lane];
        #pragma unroll
        for (int i = 0; i < 4; ++i) ao[i] = fmaf(meanF[wv][i][k], w, ao[i]);
    }
    #pragma unroll
    for (int i = 0; i < 4; ++i) {
        float r = fmaxf(ao[i], 0.f);
        __hip_bfloat16 hb = __float2bfloat16(r);
        h1b[((nb + i) << 6) + lane] = *(unsigned short*)&hb;
    }
}

// ---- 4. layers 2+3 (R13/R15-proven): gather(h1b) + scalar-broadcast GEMM + dot(W3) ----
__global__ __launch_bounds__(256) void layer23_fused(
    const unsigned short* __restrict__ h1b,
    const int* __restrict__ csr_src, const int* __restrict__ row_start,
    const int* __restrict__ cnt, const float* __restrict__ W2,
    const float* __restrict__ b2, const float* __restrict__ W3,
    const float* __restrict__ b3, float* __restrict__ out) {
    int wv   = threadIdx.x >> 6;
    int lane = threadIdx.x & 63;
    int nb   = (blockIdx.x * 4 + wv) * 4;

    float acc[4][8];
    gather4(h1b, csr_src, row_start, cnt, nb, lane, acc);

    __shared__ __align__(16) float featL[4][4][128];   // [0,64)=self, [64,128)=mean
    #pragma unroll
    for (int i = 0; i < 4; ++i) {
        featL[wv][i][lane] = bf16u(h1b[((nb + i) << 6) + lane]);
        if (lane < 8) {
            *(float4*)&featL[wv][i][64 + lane * 8] =
                make_float4(acc[i][0], acc[i][1], acc[i][2], acc[i][3]);
            *(float4*)&featL[wv][i][64 + lane * 8 + 4] =
                make_float4(acc[i][4], acc[i][5], acc[i][6], acc[i][7]);
        }
    }
    WAVE_LDS_FENCE();

    int hh = lane >> 5;                        // half-wave id: nodes nb+hh, nb+2+hh
    int j  = lane & 31;
    float a0 = b2[j], a1 = a0;
    #pragma unroll
    for (int k = 0; k < 128; ++k) {
        float w = W2[k * 32 + j];              // lanes coalesced, reused x2
        a0 = fmaf(featL[wv][hh][k],     w, a0);
        a1 = fmaf(featL[wv][2 + hh][k], w, a1);
    }
    float w3 = W3[j];
    float c3 = b3[0];
    float v0 = fmaxf(a0, 0.f) * w3;
    float v1 = fmaxf(a1, 0.f) * w3;
    #pragma unroll
    for (int off = 1; off <= 16; off <<= 1) {
        v0 += __shfl_xor(v0, off);
        v1 += __shfl_xor(v1, off);
    }
    if (j == 0) {
        out[nb + hh]     = v0 + c3;
        out[nb + 2 + hh] = v1 + c3;
    }
}

extern "C" void kernel_launch(void* const* d_in, const int* in_sizes, int n_in,
                              void* d_out, int out_size, void* d_ws, size_t ws_size,
                              hipStream_t stream) {
    const float* x   = (const float*)d_in[0];
    const int*   ei  = (const int*)d_in[1];
    const int*   src = ei;
    const int*   dst = ei + N_EDGES;
    const float* W1  = (const float*)d_in[2];
    const float* b1  = (const float*)d_in[3];
    const float* W2  = (const float*)d_in[4];
    const float* b2  = (const float*)d_in[5];
    const float* W3  = (const float*)d_in[6];
    const float* b3  = (const float*)d_in[7];
    float* out = (float*)d_out;

    // ws (~52 MB): cursor_rel[512] | cnt | row_start | binned u32[NB<<13] 12.8MB |
    //   csr_src[NB<<13] 12.8MB | xb bf16 12.8MB | h1b bf16 12.8MB
    char* ws = (char*)d_ws;
    auto align = [](size_t v) { return (v + 255) & ~(size_t)255; };
    size_t o = 0;
    int* cursor_rel = (int*)(ws + o); o = align(o + 512 * 4);
    int* cnt       = (int*)(ws + o); o = align(o + (size_t)N_NODES * 4);
    int* row_start = (int*)(ws + o); o = align(o + (size_t)N_NODES * 4);
    unsigned* binned = (unsigned*)(ws + o); o = align(o + ((size_t)NB << CAPLOG) * 4);
    int* csr_src   = (int*)(ws + o); o = align(o + ((size_t)NB << CAPLOG) * 4);
    unsigned short* xb  = (unsigned short*)(ws + o); o = align(o + (size_t)N_NODES * 64 * 2);
    unsigned short* h1b = (unsigned short*)(ws + o); o = align(o + (size_t)N_NODES * 64 * 2);

    (void)hipMemsetAsync(cursor_rel, 0, 512 * sizeof(int), stream);

    bin_pad_kernel<<<NBLK_A + PAD_BLOCKS, 1024, 0, stream>>>(src, dst, cursor_rel,
                                                             binned, x, xb);
    bucket_fine<<<NB, 1024, 0, stream>>>(binned, cursor_rel, cnt, row_start, csr_src);

    layer1_fused<<<N_NODES / 16, 256, 0, stream>>>(xb, csr_src, row_start, cnt,
                                                   W1, b1, h1b);
    layer23_fused<<<N_NODES / 16, 256, 0, stream>>>(h1b, csr_src, row_start, cnt,
                                                    W2, b2, W3, b3, out);
}

// Round 2
// 249.611 us; speedup vs baseline: 1.2748x; 1.2748x over previous
//
#include <hip/hip_runtime.h>
#include <hip/hip_bf16.h>

#define N_NODES 100000
#define N_EDGES 1600000
#define IN_CH 50
#define NPB 256                                   // nodes per bucket (dst >> 8)
#define NB ((N_NODES + NPB - 1) / NPB)            // 391 buckets
#define CAPLOG 13                                 // 8192 slots/bucket (max ~4.4K used)
#define EPB 4096
#define NBLK_A ((N_EDGES + EPB - 1) / EPB)        // 391 bin blocks
#define PAD_BLOCKS ((N_NODES * 64) / 1024)        // 6250 pad blocks (1024 thr)

// ---- 1. bin edges into fixed-capacity buckets (+ extra blocks: pad x->xb bf16) ----
// cursor_rel[b] is RELATIVE (starts 0 via memset); slot = (b<<CAPLOG) + rel.
__global__ __launch_bounds__(1024) void bin_pad_kernel(
    const int* __restrict__ src, const int* __restrict__ dst,
    int* __restrict__ cursor_rel, unsigned* __restrict__ binned,
    const float* __restrict__ x, unsigned short* __restrict__ xb) {
    if (blockIdx.x >= NBLK_A) {                    // pad lane
        int t = (blockIdx.x - NBLK_A) * 1024 + threadIdx.x;  // < N_NODES*64
        int n = t >> 6, c = t & 63;
        float v = (c < IN_CH) ? x[n * IN_CH + c] : 0.0f;
        __hip_bfloat16 hb = __float2bfloat16(v);
        xb[t] = *(unsigned short*)&hb;
        return;
    }
    __shared__ int bc[NB];
    __shared__ int boff[NB];
    int t = threadIdx.x;
    if (t < NB) bc[t] = 0;
    __syncthreads();
    int e0 = blockIdx.x * EPB;
    int e1 = min(e0 + EPB, N_EDGES);
    for (int i = e0 + t; i < e1; i += 1024)
        atomicAdd(&bc[dst[i] >> 8], 1);
    __syncthreads();
    if (t < NB) {
        int v = bc[t];
        int rel = v ? atomicAdd(&cursor_rel[t], v) : 0;
        boff[t] = (t << CAPLOG) + rel;
        bc[t] = 0;                                 // reuse as local cursor
    }
    __syncthreads();
    for (int i = e0 + t; i < e1; i += 1024) {
        int d = dst[i];
        int b = d >> 8;
        int k = atomicAdd(&bc[b], 1);
        binned[boff[b] + k] = ((unsigned)(d & 255) << 17) | (unsigned)src[i];
    }
}

// ---- 2. per-bucket fine sort (u32 payload) -> cnt, row_start, csr_src ----
__global__ __launch_bounds__(1024) void bucket_fine(
    const unsigned* __restrict__ binned, const int* __restrict__ cursor_rel,
    int* __restrict__ cnt, int* __restrict__ row_start, int* __restrict__ csr_src) {
    __shared__ int lcnt[NPB];
    __shared__ int lofs[NPB];
    __shared__ int sc[NPB];
    int t = threadIdx.x;
    int b = blockIdx.x;
    int nbase = b * NPB;
    int bbase = b << CAPLOG;
    int ecnt  = cursor_rel[b];
    if (t < NPB) lcnt[t] = 0;
    __syncthreads();
    for (int i = t; i < ecnt; i += 1024)
        atomicAdd(&lcnt[(binned[bbase + i] >> 17) & 255], 1);
    __syncthreads();
    int v = (t < NPB) ? lcnt[t] : 0;
    if (t < NPB) sc[t] = v;
    __syncthreads();
    for (int off = 1; off < NPB; off <<= 1) {      // Hillis-Steele over 256
        int tmp = (t < NPB && t >= off) ? sc[t - off] : 0;
        __syncthreads();
        if (t < NPB) sc[t] += tmp;
        __syncthreads();
    }
    if (t < NPB) {
        int excl = sc[t] - v;
        lofs[t] = excl;
        int n = nbase + t;
        if (n < N_NODES) { cnt[n] = v; row_start[n] = bbase + excl; }
    }
    __syncthreads();
    for (int i = t; i < ecnt; i += 1024) {
        unsigned p = binned[bbase + i];
        int d = (int)((p >> 17) & 255);
        int k = atomicAdd(&lofs[d], 1);
        csr_src[bbase + k] = (int)(p & 0x1FFFFu);
    }
}

// unpack 8 bf16 from uint4, predicated fma into acc[0..8)
__device__ __forceinline__ void upadd8(float* a, uint4 v, float p) {
    a[0] = fmaf(p, __uint_as_float(v.x << 16), a[0]);
    a[1] = fmaf(p, __uint_as_float(v.x & 0xffff0000u), a[1]);
    a[2] = fmaf(p, __uint_as_float(v.y << 16), a[2]);
    a[3] = fmaf(p, __uint_as_float(v.y & 0xffff0000u), a[3]);
    a[4] = fmaf(p, __uint_as_float(v.z << 16), a[4]);
    a[5] = fmaf(p, __uint_as_float(v.z & 0xffff0000u), a[5]);
    a[6] = fmaf(p, __uint_as_float(v.w << 16), a[6]);
    a[7] = fmaf(p, __uint_as_float(v.w & 0xffff0000u), a[7]);
}

// wave-local LDS fence: LDS ops of one wave complete in order; no block barrier.
#define WAVE_LDS_FENCE() __asm__ volatile("s_waitcnt lgkmcnt(0)" ::: "memory")

// Gather-mean of 2 nodes per wave (R2): ALL 4 chunk loads are unconditional and
// issued before any FMA (sv defaults to 0 -> row 0, predicated off by p), giving
// 4 loads in flight with one stall per chunk while staying under the 64-VGPR
// 8-waves/SIMD cliff (R1 lesson: 128 VGPR double-buffer halved occupancy).
__device__ __forceinline__ void gather2(
    const unsigned short* __restrict__ featb, const int* __restrict__ csr_src,
    const int* __restrict__ row_start, const int* __restrict__ cnt,
    int nb, int lane, float acc[2][8]) {
    int g  = lane >> 3;
    int cw = (lane & 7) * 8;
    int start[2], deg[2], sv[2];
    #pragma unroll
    for (int i = 0; i < 2; ++i) {
        start[i] = row_start[nb + i];
        deg[i]   = cnt[nb + i];
        #pragma unroll
        for (int c = 0; c < 8; ++c) acc[i][c] = 0.f;
    }
    int dmax = max(deg[0], deg[1]);
    #pragma unroll
    for (int i = 0; i < 2; ++i)
        sv[i] = (lane < deg[i]) ? csr_src[start[i] + lane] : 0;

    #pragma unroll
    for (int cb = 0; cb < 64; cb += 16) {
        if (cb >= dmax) break;                 // wave-uniform
        // indices for the whole chunk first (DS ops), then 4 global loads
        int s00 = __shfl(sv[0], cb + g);
        int s01 = __shfl(sv[0], cb + 8 + g);
        int s10 = __shfl(sv[1], cb + g);
        int s11 = __shfl(sv[1], cb + 8 + g);
        uint4 v00 = *(const uint4*)(featb + s00 * 64 + cw);
        uint4 v01 = *(const uint4*)(featb + s01 * 64 + cw);
        uint4 v10 = *(const uint4*)(featb + s10 * 64 + cw);
        uint4 v11 = *(const uint4*)(featb + s11 * 64 + cw);
        int rem0 = deg[0] - cb;
        int rem1 = deg[1] - cb;
        upadd8(acc[0], v00, (g < rem0) ? 1.f : 0.f);
        upadd8(acc[0], v01, (g + 8 < rem0) ? 1.f : 0.f);
        upadd8(acc[1], v10, (g < rem1) ? 1.f : 0.f);
        upadd8(acc[1], v11, (g + 8 < rem1) ? 1.f : 0.f);
    }
    if (dmax > 64) {                           // rare tail (Poisson(16): ~never)
        for (int i = 0; i < 2; ++i) {
            for (int c0 = 64; c0 < deg[i]; c0 += 64) {
                int rem = deg[i] - c0; if (rem > 64) rem = 64;
                int sx = (lane < rem) ? csr_src[start[i] + c0 + lane] : 0;
                for (int cb = 0; cb < rem; cb += 16) {
                    int s0 = __shfl(sx, cb + g);
                    int s1 = __shfl(sx, cb + 8 + g);
                    float p0 = (cb + g < rem) ? 1.f : 0.f;
                    float p1 = (cb + 8 + g < rem) ? 1.f : 0.f;
                    uint4 v0 = *(const uint4*)(featb + s0 * 64 + cw);
                    uint4 v1 = *(const uint4*)(featb + s1 * 64 + cw);
                    upadd8(acc[i], v0, p0);
                    upadd8(acc[i], v1, p1);
                }
            }
        }
    }
    #pragma unroll
    for (int i = 0; i < 2; ++i) {
        float inv = 1.0f / fmaxf((float)deg[i], 1.0f);
        #pragma unroll
        for (int c = 0; c < 8; ++c) {
            float t = acc[i][c];
            t += __shfl_xor(t, 8);
            t += __shfl_xor(t, 16);
            t += __shfl_xor(t, 32);
            acc[i][c] = t * inv;
        }
    }
}

__device__ __forceinline__ float bf16u(unsigned short u) {
    return __uint_as_float(((unsigned)u) << 16);
}

// ---- 3. layer 1: 2 nodes/wave; gather(xb) + scalar-broadcast GEMM ----
__global__ __launch_bounds__(256, 8) void layer1_fused(
    const unsigned short* __restrict__ xb,
    const int* __restrict__ csr_src, const int* __restrict__ row_start,
    const int* __restrict__ cnt, const float* __restrict__ W1,
    const float* __restrict__ b1, unsigned short* __restrict__ h1b) {
    int wv   = threadIdx.x >> 6;
    int lane = threadIdx.x & 63;
    int nb   = (blockIdx.x * 4 + wv) * 2;      // N_NODES % 8 == 0

    float acc[2][8];
    gather2(xb, csr_src, row_start, cnt, nb, lane, acc);

    __shared__ __align__(16) float selfF[4][2][64];
    __shared__ __align__(16) float meanF[4][2][64];
    #pragma unroll
    for (int i = 0; i < 2; ++i) {
        selfF[wv][i][lane] = bf16u(xb[((nb + i) << 6) + lane]);
        if (lane < 8) {
            *(float4*)&meanF[wv][i][lane * 8] =
                make_float4(acc[i][0], acc[i][1], acc[i][2], acc[i][3]);
            *(float4*)&meanF[wv][i][lane * 8 + 4] =
                make_float4(acc[i][4], acc[i][5], acc[i][6], acc[i][7]);
        }
    }
    WAVE_LDS_FENCE();

    float ao[2];
    float bb = b1[lane];
    #pragma unroll
    for (int i = 0; i < 2; ++i) ao[i] = bb;
    #pragma unroll
    for (int k = 0; k < IN_CH; ++k) {
        float w = W1[k * 64 + lane];           // lanes coalesced, reused x2
        #pragma unroll
        for (int i = 0; i < 2; ++i) ao[i] = fmaf(selfF[wv][i][k], w, ao[i]);
    }
    #pragma unroll
    for (int k = 0; k < IN_CH; ++k) {
        float w = W1[(IN_CH + k) * 64 + lane];
        #pragma unroll
        for (int i = 0; i < 2; ++i) ao[i] = fmaf(meanF[wv][i][k], w, ao[i]);
    }
    #pragma unroll
    for (int i = 0; i < 2; ++i) {
        float r = fmaxf(ao[i], 0.f);
        __hip_bfloat16 hb = __float2bfloat16(r);
        h1b[((nb + i) << 6) + lane] = *(unsigned short*)&hb;
    }
}

// ---- 4. layers 2+3: 2 nodes/wave; gather(h1b) + scalar-broadcast GEMM + dot(W3) ----
__global__ __launch_bounds__(256, 8) void layer23_fused(
    const unsigned short* __restrict__ h1b,
    const int* __restrict__ csr_src, const int* __restrict__ row_start,
    const int* __restrict__ cnt, const float* __restrict__ W2,
    const float* __restrict__ b2, const float* __restrict__ W3,
    const float* __restrict__ b3, float* __restrict__ out) {
    int wv   = threadIdx.x >> 6;
    int lane = threadIdx.x & 63;
    int nb   = (blockIdx.x * 4 + wv) * 2;

    float acc[2][8];
    gather2(h1b, csr_src, row_start, cnt, nb, lane, acc);

    __shared__ __align__(16) float featL[4][2][128];   // [0,64)=self, [64,128)=mean
    #pragma unroll
    for (int i = 0; i < 2; ++i) {
        featL[wv][i][lane] = bf16u(h1b[((nb + i) << 6) + lane]);
        if (lane < 8) {
            *(float4*)&featL[wv][i][64 + lane * 8] =
                make_float4(acc[i][0], acc[i][1], acc[i][2], acc[i][3]);
            *(float4*)&featL[wv][i][64 + lane * 8 + 4] =
                make_float4(acc[i][4], acc[i][5], acc[i][6], acc[i][7]);
        }
    }
    WAVE_LDS_FENCE();

    int hh = lane >> 5;                        // half-wave id: node nb+hh
    int j  = lane & 31;
    float a0 = b2[j];
    #pragma unroll
    for (int k = 0; k < 128; ++k) {
        float w = W2[k * 32 + j];              // lanes coalesced, reused x2 halves
        a0 = fmaf(featL[wv][hh][k], w, a0);
    }
    float w3 = W3[j];
    float c3 = b3[0];
    float v0 = fmaxf(a0, 0.f) * w3;
    #pragma unroll
    for (int off = 1; off <= 16; off <<= 1)
        v0 += __shfl_xor(v0, off);
    if (j == 0)
        out[nb + hh] = v0 + c3;
}

extern "C" void kernel_launch(void* const* d_in, const int* in_sizes, int n_in,
                              void* d_out, int out_size, void* d_ws, size_t ws_size,
                              hipStream_t stream) {
    const float* x   = (const float*)d_in[0];
    const int*   ei  = (const int*)d_in[1];
    const int*   src = ei;
    const int*   dst = ei + N_EDGES;
    const float* W1  = (const float*)d_in[2];
    const float* b1  = (const float*)d_in[3];
    const float* W2  = (const float*)d_in[4];
    const float* b2  = (const float*)d_in[5];
    const float* W3  = (const float*)d_in[6];
    const float* b3  = (const float*)d_in[7];
    float* out = (float*)d_out;

    // ws (~52 MB): cursor_rel[512] | cnt | row_start | binned u32[NB<<13] 12.8MB |
    //   csr_src[NB<<13] 12.8MB | xb bf16 12.8MB | h1b bf16 12.8MB
    char* ws = (char*)d_ws;
    auto align = [](size_t v) { return (v + 255) & ~(size_t)255; };
    size_t o = 0;
    int* cursor_rel = (int*)(ws + o); o = align(o + 512 * 4);
    int* cnt       = (int*)(ws + o); o = align(o + (size_t)N_NODES * 4);
    int* row_start = (int*)(ws + o); o = align(o + (size_t)N_NODES * 4);
    unsigned* binned = (unsigned*)(ws + o); o = align(o + ((size_t)NB << CAPLOG) * 4);
    int* csr_src   = (int*)(ws + o); o = align(o + ((size_t)NB << CAPLOG) * 4);
    unsigned short* xb  = (unsigned short*)(ws + o); o = align(o + (size_t)N_NODES * 64 * 2);
    unsigned short* h1b = (unsigned short*)(ws + o); o = align(o + (size_t)N_NODES * 64 * 2);

    (void)hipMemsetAsync(cursor_rel, 0, 512 * sizeof(int), stream);

    bin_pad_kernel<<<NBLK_A + PAD_BLOCKS, 1024, 0, stream>>>(src, dst, cursor_rel,
                                                             binned, x, xb);
    bucket_fine<<<NB, 1024, 0, stream>>>(binned, cursor_rel, cnt, row_start, csr_src);

    layer1_fused<<<N_NODES / 8, 256, 0, stream>>>(xb, csr_src, row_start, cnt,
                                                  W1, b1, h1b);
    layer23_fused<<<N_NODES / 8, 256, 0, stream>>>(h1b, csr_src, row_start, cnt,
                                                   W2, b2, W3, b3, out);
}